// Round 23
// baseline (59.766 us; speedup 1.0000x reference)
//
#include <hip/hip_runtime.h>
#include <hip/hip_bf16.h>

typedef _Float16 half8 __attribute__((ext_vector_type(8)));
typedef float f32x4 __attribute__((ext_vector_type(4)));
typedef unsigned int u32x4 __attribute__((ext_vector_type(4)));

#define N_U      4096
#define N_L      65536
#define NZ       32
#define NSPLIT   256                  // L splits (grid.x of kA)
#define LSLICE   (N_L / NSPLIT)       // 256 L rows per block -> 16 tiles
#define NT       (LSLICE / 16)        // 16 L-tiles per block
#define UT       16                   // u-tiles per wave (16 MFMA per A-load)
#define BM       1024                 // U rows per kA block (4 waves x 16 x 16)
#define GY       (N_U / BM)           // 4

// workspace layout: only the atomic-max keys
#define OFF_P1   0                            // u32 P1key[N_U] (16 KB)

// Order-preserving float <-> uint key (monotone for all finite floats)
__device__ __forceinline__ unsigned int f2key(float f) {
    unsigned int u = __float_as_uint(f);
    return (u & 0x80000000u) ? ~u : (u | 0x80000000u);
}
__device__ __forceinline__ float key2f(unsigned int k) {
    unsigned int u = (k & 0x80000000u) ? (k & 0x7FFFFFFFu) : ~k;
    return __uint_as_float(u);
}

// ---------------------------------------------------------------------------
// Tiny init: P1key = 0 (key-space -inf). A kernel, NOT hipMemsetAsync —
// R22 showed the runtime's fillBuffer dispatch has a ~40 us fixed cost in
// the timed/graph path; a plain kernel launch is ~2 us.
__global__ __launch_bounds__(256) void kInit(unsigned int* __restrict__ P1key) {
    P1key[blockIdx.x * 256 + threadIdx.x] = 0u;
}

// ---------------------------------------------------------------------------
// Heavy kernel — self-contained (R22-proven: kA+kB ~19.7 us): stages L
// directly from the f32 input (convert + row-norm in the stage pass) and
// converts its own U fragments from Uz. No kPre, no ws staging arrays, no
// cold first-touch. Hot loop: R17/R21 proven (LDS lane-linear layout,
// UT=16 pinned bfrag, wave stagger, builtin MFMA + arch-VGPR pin).
__global__ __launch_bounds__(256)
__attribute__((amdgpu_waves_per_eu(4, 4)))
void kA(const float* __restrict__ Lz,
        const float* __restrict__ Uz,
        unsigned int* __restrict__ P1key) {
    __shared__ __align__(16) unsigned char sm[LSLICE * 64 + LSLICE * 4];
    float* slsq = (float*)(sm + LSLICE * 64);

    const int tid  = threadIdx.x;
    const int lane = tid & 63;
    const int wave = tid >> 6;
    const int g    = lane >> 4;    // k-chunk 0..3 (k = g*8+e, same perm A and B)
    const int lc   = lane & 15;

    const int ubase = blockIdx.y * BM + wave * (UT * 16);
    const int lbase = blockIdx.x * LSLICE;

    // ---- stage: thread t -> L row t. f32 load, f16 convert, -0.5*||l||^2.
    // Fragment-major LDS layout: row r chunk j at (r>>4)*1024 + j*256 +
    // (r&15)*16  ->  a wave's A-read is sm + pt*1024 + lane*16 (conflict-free)
    {
        const f32x4* src = (const f32x4*)(Lz + (size_t)(lbase + tid) * NZ);
        unsigned char* dst = sm + ((tid >> 4) * 1024) + ((tid & 15) * 16);
        float s = 0.f;
#pragma unroll
        for (int j = 0; j < 4; ++j) {
            f32x4 a = src[2 * j], b = src[2 * j + 1];
            s = fmaf(a[0], a[0], s); s = fmaf(a[1], a[1], s);
            s = fmaf(a[2], a[2], s); s = fmaf(a[3], a[3], s);
            s = fmaf(b[0], b[0], s); s = fmaf(b[1], b[1], s);
            s = fmaf(b[2], b[2], s); s = fmaf(b[3], b[3], s);
            *(half8*)(dst + j * 256) =
                (half8){(_Float16)a[0], (_Float16)a[1], (_Float16)a[2], (_Float16)a[3],
                        (_Float16)b[0], (_Float16)b[1], (_Float16)b[2], (_Float16)b[3]};
        }
        slsq[tid] = -0.5f * s;
    }

    // ---- U fragments straight from f32 input (R1-proven conversion path)
    half8 bfrag[UT];
#pragma unroll
    for (int t = 0; t < UT; ++t) {
        const f32x4* p = (const f32x4*)(Uz + (size_t)(ubase + t * 16 + lc) * NZ + g * 8);
        f32x4 a = p[0], b = p[1];
        bfrag[t] = (half8){(_Float16)a[0], (_Float16)a[1], (_Float16)a[2], (_Float16)a[3],
                           (_Float16)b[0], (_Float16)b[1], (_Float16)b[2], (_Float16)b[3]};
    }
    // Pin B-fragments: opaque non-rematerializable defs.
#pragma unroll
    for (int t = 0; t < UT; ++t)
        asm volatile("" : "+v"(bfrag[t]));

    float m[UT];
#pragma unroll
    for (int t = 0; t < UT; ++t) m[t] = -INFINITY;

    __syncthreads();

    const unsigned char* abase = sm + lane * 16;

#pragma unroll 2
    for (int lt = 0; lt < NT; ++lt) {
        const int pt = (lt + wave * 4) & (NT - 1);   // per-wave phase stagger
        half8 a = *(const half8*)(abase + pt * 1024);    // contiguous 1KB/wave
        f32x4 c = *(const f32x4*)(slsq + pt * 16 + g * 4);   // 16-lane broadcast
#pragma unroll
        for (int t = 0; t < UT; ++t) {
            f32x4 x = __builtin_amdgcn_mfma_f32_16x16x32_f16(a, bfrag[t], c, 0, 0, 0);
            asm volatile("" : "+v"(x));   // keep D in arch VGPRs
            float y = fmaxf(fmaxf(x[0], x[1]), x[2]);        // v_max3
            m[t] = fmaxf(fmaxf(y, x[3]), m[t]);              // v_max3
        }
    }

#pragma unroll
    for (int t = 0; t < UT; ++t) {
        float v = m[t];
        v = fmaxf(v, __shfl_xor(v, 16));
        v = fmaxf(v, __shfl_xor(v, 32));
        if (g == 0)
            atomicMax(&P1key[ubase + t * 16 + lc], f2key(v));
    }
}

// ---------------------------------------------------------------------------
// Single-block finisher: ||u||^2 from Uz, dd, global min/max, normalize.
__global__ __launch_bounds__(1024) void kB(const unsigned int* __restrict__ P1key,
                                           const float* __restrict__ Uz,
                                           float* __restrict__ out) {
    const int t    = threadIdx.x;       // 0..1023, each handles 4 u's
    const int lane = t & 63;
    const int wid  = t >> 6;

    u32x4 kv = ((const u32x4*)P1key)[t];

    float dd[4], lmin = INFINITY, lmax = -INFINITY;
#pragma unroll
    for (int j = 0; j < 4; ++j) {
        const int u = t * 4 + j;
        const f32x4* p = (const f32x4*)(Uz + (size_t)u * NZ);
        float s = 0.f;
#pragma unroll
        for (int q = 0; q < 8; ++q) {
            f32x4 v = p[q];
            s = fmaf(v[0], v[0], s); s = fmaf(v[1], v[1], s);
            s = fmaf(v[2], v[2], s); s = fmaf(v[3], v[3], s);
        }
        float M   = key2f(kv[j]);                       // max(u.l - 0.5||l||^2)
        float sq  = fmaxf(fmaf(-2.f, M, s), 0.f);       // min squared distance
        float dens = -0.5f * s - 29.406033062549525f;   // -0.5||u||^2-16log2pi
        dd[j] = expf(dens) * (sqrtf(sq) + 1e-18f);
        lmin = fminf(lmin, dd[j]);
        lmax = fmaxf(lmax, dd[j]);
    }

    __shared__ float smn[16], smx[16];
#pragma unroll
    for (int o = 1; o < 64; o <<= 1) {
        lmin = fminf(lmin, __shfl_xor(lmin, o));
        lmax = fmaxf(lmax, __shfl_xor(lmax, o));
    }
    if (lane == 0) { smn[wid] = lmin; smx[wid] = lmax; }
    __syncthreads();
    if (wid == 0) {
        float a = (lane < 16) ? smn[lane] : INFINITY;
        float b = (lane < 16) ? smx[lane] : -INFINITY;
#pragma unroll
        for (int o = 1; o < 16; o <<= 1) {
            a = fminf(a, __shfl_xor(a, o));
            b = fmaxf(b, __shfl_xor(b, o));
        }
        if (lane == 0) { smn[0] = a; smx[0] = b; }
    }
    __syncthreads();
    float mn = smn[0], mx = smx[0];
    float inv = 1.f / ((mx - mn) + 1e-18f);

    f32x4 o4 = (f32x4){(dd[0] - mn) * inv, (dd[1] - mn) * inv,
                       (dd[2] - mn) * inv, (dd[3] - mn) * inv};
    ((f32x4*)out)[t] = o4;
}

// ---------------------------------------------------------------------------
extern "C" void kernel_launch(void* const* d_in, const int* in_sizes, int n_in,
                              void* d_out, int out_size, void* d_ws, size_t ws_size,
                              hipStream_t stream) {
    const float* Uz = (const float*)d_in[1];
    const float* Lz = (const float*)d_in[2];
    float* out = (float*)d_out;
    unsigned char* ws = (unsigned char*)d_ws;

    unsigned int* P1key = (unsigned int*)(ws + OFF_P1);

    kInit<<<N_U / 256, 256, 0, stream>>>(P1key);
    dim3 grid(NSPLIT, GY);   // 256 x 4 = 1024 blocks
    kA<<<grid, 256, 0, stream>>>(Lz, Uz, P1key);
    kB<<<1, 1024, 0, stream>>>(P1key, Uz, out);
}

// Round 24
// 48.394 us; speedup vs baseline: 1.2350x; 1.2350x over previous
//
#include <hip/hip_runtime.h>
#include <hip/hip_bf16.h>

typedef _Float16 half8 __attribute__((ext_vector_type(8)));
typedef float f32x4 __attribute__((ext_vector_type(4)));
typedef unsigned int u32x4 __attribute__((ext_vector_type(4)));

#define N_U      4096
#define N_L      65536
#define NZ       32
#define NSPLIT   256                  // L splits (grid.x of kA)
#define LSLICE   (N_L / NSPLIT)       // 256 L rows per block -> 16 tiles
#define NT       (LSLICE / 16)        // 16 L-tiles per block
#define UT       16                   // u-tiles per wave (16 MFMA per A-load)
#define BM       1024                 // U rows per kA block (4 waves x 16 x 16)
#define GY       (N_U / BM)           // 4

// workspace layout
#define OFF_P1   0                            // u32 P1key[N_U] (16 KB)
#define OFF_UF   (32 * 1024)                  // _Float16 Uf16[N_U][32] (256 KB)

// Order-preserving float <-> uint key (monotone for all finite floats)
__device__ __forceinline__ unsigned int f2key(float f) {
    unsigned int u = __float_as_uint(f);
    return (u & 0x80000000u) ? ~u : (u | 0x80000000u);
}
__device__ __forceinline__ float key2f(unsigned int k) {
    unsigned int u = (k & 0x80000000u) ? (k & 0x7FFFFFFFu) : ~k;
    return __uint_as_float(u);
}

// ---------------------------------------------------------------------------
// Tiny pre-pass: U -> f16 (so kA's 16 pinned bfrag are direct 16B loads into
// final registers — R22/R23's inline f32->f16 conversion of 16 tiles forced
// ~128 VGPRs of hoisted load temps + 64 pinned regs > the 128 budget ->
// prologue scratch spill, +25 us). Also zeroes P1key. 16 blocks, ~2 us.
__global__ __launch_bounds__(256) void kPreU(const float* __restrict__ Uz,
                                             _Float16* __restrict__ Uf16,
                                             unsigned int* __restrict__ P1key) {
    int u = blockIdx.x * 256 + threadIdx.x;   // one U row per thread
    const f32x4* src = (const f32x4*)(Uz + (size_t)u * NZ);
    _Float16* dst = Uf16 + (size_t)u * NZ;
#pragma unroll
    for (int j = 0; j < 4; ++j) {
        f32x4 a = src[2 * j], b = src[2 * j + 1];
        *(half8*)(dst + j * 8) =
            (half8){(_Float16)a[0], (_Float16)a[1], (_Float16)a[2], (_Float16)a[3],
                    (_Float16)b[0], (_Float16)b[1], (_Float16)b[2], (_Float16)b[3]};
    }
    P1key[u] = 0u;   // key-space -inf
}

// ---------------------------------------------------------------------------
// Heavy kernel: stages L directly from f32 input (convert + row-norm in the
// stage pass — 8 temps, consumed straight into LDS, no pressure), bfrag from
// Uf16 (direct half8 loads, R21-proven). Hot loop: R17/R21 proven (lane-
// linear LDS, UT=16 pinned bfrag, wave stagger, builtin MFMA + arch-VGPR pin).
__global__ __launch_bounds__(256)
__attribute__((amdgpu_waves_per_eu(4, 4)))
void kA(const float* __restrict__ Lz,
        const _Float16* __restrict__ Uf16,
        unsigned int* __restrict__ P1key) {
    __shared__ __align__(16) unsigned char sm[LSLICE * 64 + LSLICE * 4];
    float* slsq = (float*)(sm + LSLICE * 64);

    const int tid  = threadIdx.x;
    const int lane = tid & 63;
    const int wave = tid >> 6;
    const int g    = lane >> 4;    // k-chunk 0..3 (k = g*8+e, same perm A and B)
    const int lc   = lane & 15;

    const int ubase = blockIdx.y * BM + wave * (UT * 16);
    const int lbase = blockIdx.x * LSLICE;

    // ---- stage: thread t -> L row t. f32 load, f16 convert, -0.5*||l||^2.
    // Fragment-major LDS layout: row r chunk j at (r>>4)*1024 + j*256 +
    // (r&15)*16  ->  a wave's A-read is sm + pt*1024 + lane*16 (conflict-free)
    {
        const f32x4* src = (const f32x4*)(Lz + (size_t)(lbase + tid) * NZ);
        unsigned char* dst = sm + ((tid >> 4) * 1024) + ((tid & 15) * 16);
        float s = 0.f;
#pragma unroll
        for (int j = 0; j < 4; ++j) {
            f32x4 a = src[2 * j], b = src[2 * j + 1];
            s = fmaf(a[0], a[0], s); s = fmaf(a[1], a[1], s);
            s = fmaf(a[2], a[2], s); s = fmaf(a[3], a[3], s);
            s = fmaf(b[0], b[0], s); s = fmaf(b[1], b[1], s);
            s = fmaf(b[2], b[2], s); s = fmaf(b[3], b[3], s);
            *(half8*)(dst + j * 256) =
                (half8){(_Float16)a[0], (_Float16)a[1], (_Float16)a[2], (_Float16)a[3],
                        (_Float16)b[0], (_Float16)b[1], (_Float16)b[2], (_Float16)b[3]};
        }
        slsq[tid] = -0.5f * s;
    }

    // ---- U fragments: direct half8 loads into final regs (no temp blowup)
    half8 bfrag[UT];
#pragma unroll
    for (int t = 0; t < UT; ++t)
        bfrag[t] = *(const half8*)(Uf16 + (size_t)(ubase + t * 16 + lc) * NZ + g * 8);
    // Pin B-fragments: opaque non-rematerializable defs.
#pragma unroll
    for (int t = 0; t < UT; ++t)
        asm volatile("" : "+v"(bfrag[t]));

    float m[UT];
#pragma unroll
    for (int t = 0; t < UT; ++t) m[t] = -INFINITY;

    __syncthreads();

    const unsigned char* abase = sm + lane * 16;

#pragma unroll 2
    for (int lt = 0; lt < NT; ++lt) {
        const int pt = (lt + wave * 4) & (NT - 1);   // per-wave phase stagger
        half8 a = *(const half8*)(abase + pt * 1024);    // contiguous 1KB/wave
        f32x4 c = *(const f32x4*)(slsq + pt * 16 + g * 4);   // 16-lane broadcast
#pragma unroll
        for (int t = 0; t < UT; ++t) {
            f32x4 x = __builtin_amdgcn_mfma_f32_16x16x32_f16(a, bfrag[t], c, 0, 0, 0);
            asm volatile("" : "+v"(x));   // keep D in arch VGPRs
            float y = fmaxf(fmaxf(x[0], x[1]), x[2]);        // v_max3
            m[t] = fmaxf(fmaxf(y, x[3]), m[t]);              // v_max3
        }
    }

#pragma unroll
    for (int t = 0; t < UT; ++t) {
        float v = m[t];
        v = fmaxf(v, __shfl_xor(v, 16));
        v = fmaxf(v, __shfl_xor(v, 32));
        if (g == 0)
            atomicMax(&P1key[ubase + t * 16 + lc], f2key(v));
    }
}

// ---------------------------------------------------------------------------
// Single-block finisher: ||u||^2 from Uz, dd, global min/max, normalize.
__global__ __launch_bounds__(1024) void kB(const unsigned int* __restrict__ P1key,
                                           const float* __restrict__ Uz,
                                           float* __restrict__ out) {
    const int t    = threadIdx.x;       // 0..1023, each handles 4 u's
    const int lane = t & 63;
    const int wid  = t >> 6;

    u32x4 kv = ((const u32x4*)P1key)[t];

    float dd[4], lmin = INFINITY, lmax = -INFINITY;
#pragma unroll
    for (int j = 0; j < 4; ++j) {
        const int u = t * 4 + j;
        const f32x4* p = (const f32x4*)(Uz + (size_t)u * NZ);
        float s = 0.f;
#pragma unroll
        for (int q = 0; q < 8; ++q) {
            f32x4 v = p[q];
            s = fmaf(v[0], v[0], s); s = fmaf(v[1], v[1], s);
            s = fmaf(v[2], v[2], s); s = fmaf(v[3], v[3], s);
        }
        float M   = key2f(kv[j]);                       // max(u.l - 0.5||l||^2)
        float sq  = fmaxf(fmaf(-2.f, M, s), 0.f);       // min squared distance
        float dens = -0.5f * s - 29.406033062549525f;   // -0.5||u||^2-16log2pi
        dd[j] = expf(dens) * (sqrtf(sq) + 1e-18f);
        lmin = fminf(lmin, dd[j]);
        lmax = fmaxf(lmax, dd[j]);
    }

    __shared__ float smn[16], smx[16];
#pragma unroll
    for (int o = 1; o < 64; o <<= 1) {
        lmin = fminf(lmin, __shfl_xor(lmin, o));
        lmax = fmaxf(lmax, __shfl_xor(lmax, o));
    }
    if (lane == 0) { smn[wid] = lmin; smx[wid] = lmax; }
    __syncthreads();
    if (wid == 0) {
        float a = (lane < 16) ? smn[lane] : INFINITY;
        float b = (lane < 16) ? smx[lane] : -INFINITY;
#pragma unroll
        for (int o = 1; o < 16; o <<= 1) {
            a = fminf(a, __shfl_xor(a, o));
            b = fmaxf(b, __shfl_xor(b, o));
        }
        if (lane == 0) { smn[0] = a; smx[0] = b; }
    }
    __syncthreads();
    float mn = smn[0], mx = smx[0];
    float inv = 1.f / ((mx - mn) + 1e-18f);

    f32x4 o4 = (f32x4){(dd[0] - mn) * inv, (dd[1] - mn) * inv,
                       (dd[2] - mn) * inv, (dd[3] - mn) * inv};
    ((f32x4*)out)[t] = o4;
}

// ---------------------------------------------------------------------------
extern "C" void kernel_launch(void* const* d_in, const int* in_sizes, int n_in,
                              void* d_out, int out_size, void* d_ws, size_t ws_size,
                              hipStream_t stream) {
    const float* Uz = (const float*)d_in[1];
    const float* Lz = (const float*)d_in[2];
    float* out = (float*)d_out;
    unsigned char* ws = (unsigned char*)d_ws;

    unsigned int* P1key = (unsigned int*)(ws + OFF_P1);
    _Float16*     Uf16  = (_Float16*)(ws + OFF_UF);

    kPreU<<<N_U / 256, 256, 0, stream>>>(Uz, Uf16, P1key);
    dim3 grid(NSPLIT, GY);   // 256 x 4 = 1024 blocks
    kA<<<grid, 256, 0, stream>>>(Lz, Uf16, P1key);
    kB<<<1, 1024, 0, stream>>>(P1key, Uz, out);
}

// Round 25
// 36.489 us; speedup vs baseline: 1.6379x; 1.3263x over previous
//
#include <hip/hip_runtime.h>
#include <hip/hip_bf16.h>

typedef _Float16 half8 __attribute__((ext_vector_type(8)));
typedef float f32x4 __attribute__((ext_vector_type(4)));
typedef unsigned int u32x4 __attribute__((ext_vector_type(4)));

#define N_U      4096
#define N_L      65536
#define NZ       32
#define NSPLIT   256                  // L splits (grid.x of kA)
#define LSLICE   (N_L / NSPLIT)       // 256 L rows per block -> 16 tiles
#define NT       (LSLICE / 16)        // 16 L-tiles per block
#define UT       8                    // u-tiles per wave (halved: reg headroom)
#define BM       512                  // U rows per kA block (4 waves x 8 x 16)
#define GY       (N_U / BM)           // 8 -> grid 2048 = 2 exact rounds at 4/CU

// workspace layout
#define OFF_P1   0                            // u32 P1key[N_U] (16 KB)
#define OFF_USQ  (16 * 1024)                  // float usq[N_U]  (16 KB)
#define OFF_LF   (32 * 1024)                  // _Float16 Lf16[N_L][32] (4 MB)
#define OFF_LSQ  (OFF_LF + N_L * NZ * 2)      // float lsqh[N_L] = -0.5*||l||^2
#define OFF_UF   (OFF_LSQ + N_L * 4)          // _Float16 Uf16[N_U][32]

// Order-preserving float <-> uint key (monotone for all finite floats)
__device__ __forceinline__ unsigned int f2key(float f) {
    unsigned int u = __float_as_uint(f);
    return (u & 0x80000000u) ? ~u : (u | 0x80000000u);
}
__device__ __forceinline__ float key2f(unsigned int k) {
    unsigned int u = (k & 0x80000000u) ? (k & 0x7FFFFFFFu) : ~k;
    return __uint_as_float(u);
}

// ---------------------------------------------------------------------------
// Precompute: L -> f16 + (-0.5*||l||^2); U -> f16 + ||u||^2; init P1key.
__global__ __launch_bounds__(256) void kPre(const float* __restrict__ Uz,
                                            const float* __restrict__ Lz,
                                            _Float16* __restrict__ Lf16,
                                            float* __restrict__ lsqh,
                                            _Float16* __restrict__ Uf16,
                                            float* __restrict__ usq,
                                            unsigned int* __restrict__ P1key) {
    int r = blockIdx.x * 256 + threadIdx.x;
    if (r < N_L) {
        const f32x4* src = (const f32x4*)(Lz + (size_t)r * NZ);
        _Float16* dst = Lf16 + (size_t)r * NZ;
        float s = 0.f;
#pragma unroll
        for (int j = 0; j < 4; ++j) {
            f32x4 a = src[2 * j], b = src[2 * j + 1];
            s = fmaf(a[0], a[0], s); s = fmaf(a[1], a[1], s);
            s = fmaf(a[2], a[2], s); s = fmaf(a[3], a[3], s);
            s = fmaf(b[0], b[0], s); s = fmaf(b[1], b[1], s);
            s = fmaf(b[2], b[2], s); s = fmaf(b[3], b[3], s);
            *(half8*)(dst + j * 8) =
                (half8){(_Float16)a[0], (_Float16)a[1], (_Float16)a[2], (_Float16)a[3],
                        (_Float16)b[0], (_Float16)b[1], (_Float16)b[2], (_Float16)b[3]};
        }
        lsqh[r] = -0.5f * s;
    } else if (r < N_L + N_U) {
        int u = r - N_L;
        const f32x4* src = (const f32x4*)(Uz + (size_t)u * NZ);
        _Float16* dst = Uf16 + (size_t)u * NZ;
        float s = 0.f;
#pragma unroll
        for (int j = 0; j < 4; ++j) {
            f32x4 a = src[2 * j], b = src[2 * j + 1];
            s = fmaf(a[0], a[0], s); s = fmaf(a[1], a[1], s);
            s = fmaf(a[2], a[2], s); s = fmaf(a[3], a[3], s);
            s = fmaf(b[0], b[0], s); s = fmaf(b[1], b[1], s);
            s = fmaf(b[2], b[2], s); s = fmaf(b[3], b[3], s);
            *(half8*)(dst + j * 8) =
                (half8){(_Float16)a[0], (_Float16)a[1], (_Float16)a[2], (_Float16)a[3],
                        (_Float16)b[0], (_Float16)b[1], (_Float16)b[2], (_Float16)b[3]};
        }
        usq[u] = s;
        P1key[u] = 0u;   // key-space -inf
    }
}

// ---------------------------------------------------------------------------
// Heavy kernel — R17 structure with UT=8: halves per-wave registers (bfrag 32
// + m 8 + temps ~= 64 live vs 128 budget) so the allocator has 2x slack —
// fixing R20's measured 3-blocks/CU (152 regs/wave) ragged round. Grid 2048
// at waves_per_eu(4,4)-capped 4 blocks/CU = TWO exact full-occupancy rounds.
// Lane-linear LDS stage (R21-proven conflict-free), wave stagger, builtin
// MFMA + arch-VGPR pins.
__global__ __launch_bounds__(256)
__attribute__((amdgpu_waves_per_eu(4, 4)))
void kA(const _Float16* __restrict__ Lf16,
        const float* __restrict__ lsqh,
        const _Float16* __restrict__ Uf16,
        unsigned int* __restrict__ P1key) {
    __shared__ __align__(16) unsigned char sm[LSLICE * 64 + LSLICE * 4];
    float* slsq = (float*)(sm + LSLICE * 64);

    const int tid  = threadIdx.x;
    const int lane = tid & 63;
    const int wave = tid >> 6;
    const int g    = lane >> 4;    // k-chunk 0..3 (k = g*8+e, same perm A and B)
    const int lc   = lane & 15;

    const int ubase = blockIdx.y * BM + wave * (UT * 16);
    const int lbase = blockIdx.x * LSLICE;

    // ---- stage: thread t -> L row t, fragment-major (lane-linear reads)
    {
        const half8* src = (const half8*)(Lf16 + (size_t)(lbase + tid) * NZ);
        unsigned char* dst = sm + ((tid >> 4) * 1024) + ((tid & 15) * 16);
#pragma unroll
        for (int j = 0; j < 4; ++j)
            *(half8*)(dst + j * 256) = src[j];
        slsq[tid] = lsqh[lbase + tid];
    }

    half8 bfrag[UT];
#pragma unroll
    for (int t = 0; t < UT; ++t)
        bfrag[t] = *(const half8*)(Uf16 + (size_t)(ubase + t * 16 + lc) * NZ + g * 8);
    // Pin B-fragments: opaque non-rematerializable defs.
#pragma unroll
    for (int t = 0; t < UT; ++t)
        asm volatile("" : "+v"(bfrag[t]));

    float m[UT];
#pragma unroll
    for (int t = 0; t < UT; ++t) m[t] = -INFINITY;

    __syncthreads();

    const unsigned char* abase = sm + lane * 16;

#pragma unroll 2
    for (int lt = 0; lt < NT; ++lt) {
        const int pt = (lt + wave * 4) & (NT - 1);   // per-wave phase stagger
        half8 a = *(const half8*)(abase + pt * 1024);    // contiguous 1KB/wave
        f32x4 c = *(const f32x4*)(slsq + pt * 16 + g * 4);   // 16-lane broadcast
#pragma unroll
        for (int t = 0; t < UT; ++t) {
            f32x4 x = __builtin_amdgcn_mfma_f32_16x16x32_f16(a, bfrag[t], c, 0, 0, 0);
            asm volatile("" : "+v"(x));   // keep D in arch VGPRs
            float y = fmaxf(fmaxf(x[0], x[1]), x[2]);        // v_max3
            m[t] = fmaxf(fmaxf(y, x[3]), m[t]);              // v_max3
        }
    }

#pragma unroll
    for (int t = 0; t < UT; ++t) {
        float v = m[t];
        v = fmaxf(v, __shfl_xor(v, 16));
        v = fmaxf(v, __shfl_xor(v, 32));
        if (g == 0)
            atomicMax(&P1key[ubase + t * 16 + lc], f2key(v));
    }
}

// ---------------------------------------------------------------------------
// Single-block finisher: dd, global min/max, normalize. Reads 32 KB only.
__global__ __launch_bounds__(1024) void kB(const unsigned int* __restrict__ P1key,
                                           const float* __restrict__ usq,
                                           float* __restrict__ out) {
    const int t    = threadIdx.x;       // 0..1023, each handles 4 u's
    const int lane = t & 63;
    const int wid  = t >> 6;

    u32x4 kv = ((const u32x4*)P1key)[t];
    f32x4 uq = ((const f32x4*)usq)[t];

    float dd[4], lmin = INFINITY, lmax = -INFINITY;
#pragma unroll
    for (int j = 0; j < 4; ++j) {
        float M   = key2f(kv[j]);                       // max(u.l - 0.5||l||^2)
        float sq  = fmaxf(fmaf(-2.f, M, uq[j]), 0.f);   // min squared distance
        float dens = -0.5f * uq[j] - 29.406033062549525f;
        dd[j] = expf(dens) * (sqrtf(sq) + 1e-18f);
        lmin = fminf(lmin, dd[j]);
        lmax = fmaxf(lmax, dd[j]);
    }

    __shared__ float smn[16], smx[16];
#pragma unroll
    for (int o = 1; o < 64; o <<= 1) {
        lmin = fminf(lmin, __shfl_xor(lmin, o));
        lmax = fmaxf(lmax, __shfl_xor(lmax, o));
    }
    if (lane == 0) { smn[wid] = lmin; smx[wid] = lmax; }
    __syncthreads();
    if (wid == 0) {
        float a = (lane < 16) ? smn[lane] : INFINITY;
        float b = (lane < 16) ? smx[lane] : -INFINITY;
#pragma unroll
        for (int o = 1; o < 16; o <<= 1) {
            a = fminf(a, __shfl_xor(a, o));
            b = fmaxf(b, __shfl_xor(b, o));
        }
        if (lane == 0) { smn[0] = a; smx[0] = b; }
    }
    __syncthreads();
    float mn = smn[0], mx = smx[0];
    float inv = 1.f / ((mx - mn) + 1e-18f);

    f32x4 o4 = (f32x4){(dd[0] - mn) * inv, (dd[1] - mn) * inv,
                       (dd[2] - mn) * inv, (dd[3] - mn) * inv};
    ((f32x4*)out)[t] = o4;
}

// ---------------------------------------------------------------------------
extern "C" void kernel_launch(void* const* d_in, const int* in_sizes, int n_in,
                              void* d_out, int out_size, void* d_ws, size_t ws_size,
                              hipStream_t stream) {
    const float* Uz = (const float*)d_in[1];
    const float* Lz = (const float*)d_in[2];
    float* out = (float*)d_out;
    unsigned char* ws = (unsigned char*)d_ws;

    unsigned int* P1key = (unsigned int*)(ws + OFF_P1);
    float*        usq   = (float*)(ws + OFF_USQ);
    _Float16*     Lf16  = (_Float16*)(ws + OFF_LF);
    float*        lsqh  = (float*)(ws + OFF_LSQ);
    _Float16*     Uf16  = (_Float16*)(ws + OFF_UF);

    kPre<<<(N_L + N_U + 255) / 256, 256, 0, stream>>>(Uz, Lz, Lf16, lsqh, Uf16, usq, P1key);
    dim3 grid(NSPLIT, GY);   // 256 x 8 = 2048 blocks = 2 exact rounds at 4/CU
    kA<<<grid, 256, 0, stream>>>(Lf16, lsqh, Uf16, P1key);
    kB<<<1, 1024, 0, stream>>>(P1key, usq, out);
}